// Round 1
// baseline (340.379 us; speedup 1.0000x reference)
//
#include <hip/hip_runtime.h>
#include <math.h>

#define EPSF 1e-8f
// f32 nearest to 2*pi
#define TWO_PI_F 6.28318530717958647692f

// Faithful fp32 emulation of _hvit + _phvit for one pixel.
// Precision-critical ops (hue path: divides, sincos, atan2, mod) use IEEE /
// libm-precise variants so discontinuity decisions (floor(6h), hue-wrap to
// exactly 1.0f -> hi==6 -> zero output) match the numpy/jax fp32 reference.
// cs only enters via cs/(cs+eps) (relative sensitivity ~4e-7), so it uses
// fast HW transcendentals.
__device__ __forceinline__ void hvi_pixel(float r, float g, float b, float k,
                                          float& ro, float& go, float& bo)
{
    float value = fmaxf(r, fmaxf(g, b));
    float vmin  = fminf(r, fminf(g, b));
    float diff  = value - vmin + EPSF;

    // where-chain priority: vmin==value > r==value > g==value > b==value
    bool isR = (r == value);
    bool isG = (!isR) && (g == value);

    float num  = isR ? (g - b) : (isG ? (b - r) : (r - g));
    float offs = isR ? 0.0f   : (isG ? 2.0f    : 4.0f);
    float x    = num / diff;                 // IEEE divide (matches np)
    float hue6 = offs + x;
    if (isR && x < 0.0f) hue6 = x + 6.0f;    // np mod semantics: fmod + adjust
    if (vmin == value)   hue6 = 0.0f;
    float hue = hue6 / 6.0f;                 // IEEE divide: 6.0/6.0 == 1.0 exactly

    float sat = (value == 0.0f) ? 0.0f : (value - vmin) / (value + EPSF);

    // cs: fast path is safe (see note above)
    float sv = __sinf((value * 0.5f) * 3.14159265358979323846f) + EPSF;
    float cs = __expf(k * __logf(sv));

    float ang = TWO_PI_F * hue;
    float sh, ch;
    sincosf(ang, &sh, &ch);                  // precise libm

    float X = cs * sat * ch;
    float Y = cs * sat * sh;

    // ---- _phvit ----
    float H = fminf(fmaxf(X, -1.0f), 1.0f);
    float V = fminf(fmaxf(Y, -1.0f), 1.0f);
    float v = fminf(fmaxf(value, 0.0f), 1.0f);

    // cs2 is the bit-identical expression on v==value -> reuse cs
    float csd = cs + EPSF;
    H = fminf(fmaxf(H / csd, -1.0f), 1.0f);
    V = fminf(fmaxf(V / csd, -1.0f), 1.0f);

    float t2 = atan2f(V, H) / TWO_PI_F;      // precise atan2 + IEEE divide
    float h  = (t2 < 0.0f) ? t2 + 1.0f : t2; // np mod(x, 1.0)
    float s  = fminf(fmaxf(sqrtf(H * H + V * V), 0.0f), 1.0f);

    float h6  = h * 6.0f;
    float hif = floorf(h6);
    float f   = h6 - hif;
    float pv  = v * (1.0f - s);
    float qv  = v * (1.0f - f * s);
    float tv  = v * (1.0f - (1.0f - f) * s);
    int hi = (int)hif;

    // jnp.select with default 0 (hi==6 wrap pixels fall through to zero,
    // matching the fp32 reference)
    float rr = 0.0f, gg = 0.0f, bb = 0.0f;
    rr = (hi == 0) ? v  : rr;  gg = (hi == 0) ? tv : gg;  bb = (hi == 0) ? pv : bb;
    rr = (hi == 1) ? qv : rr;  gg = (hi == 1) ? v  : gg;  bb = (hi == 1) ? pv : bb;
    rr = (hi == 2) ? pv : rr;  gg = (hi == 2) ? v  : gg;  bb = (hi == 2) ? tv : bb;
    rr = (hi == 3) ? pv : rr;  gg = (hi == 3) ? qv : gg;  bb = (hi == 3) ? v  : bb;
    rr = (hi == 4) ? tv : rr;  gg = (hi == 4) ? pv : gg;  bb = (hi == 4) ? v  : bb;
    rr = (hi == 5) ? v  : rr;  gg = (hi == 5) ? pv : gg;  bb = (hi == 5) ? qv : bb;

    ro = rr; go = gg; bo = bb;
}

// Layout: (N=16, C=3, H*W = 1<<20). Channel stride = 1M floats, image stride
// = 3M floats. One thread handles 4 consecutive pixels -> float4 per plane,
// fully coalesced (p is a multiple of 4).
extern "C" __global__ void __launch_bounds__(256)
rgb_hvi_kernel(const float* __restrict__ img, const float* __restrict__ kptr,
               float* __restrict__ out, int ngroups)
{
    int i = blockIdx.x * blockDim.x + threadIdx.x;
    if (i >= ngroups) return;
    const float k = kptr[0];

    unsigned int q = (unsigned int)i << 2;        // pixel index
    unsigned int n = q >> 20;                     // image index
    unsigned int p = q & 1048575u;                // pixel within image
    size_t base = (size_t)n * 3145728u + p;

    const float4 R = *reinterpret_cast<const float4*>(img + base);
    const float4 G = *reinterpret_cast<const float4*>(img + base + 1048576);
    const float4 B = *reinterpret_cast<const float4*>(img + base + 2097152);

    float4 Ro, Go, Bo;
    hvi_pixel(R.x, G.x, B.x, k, Ro.x, Go.x, Bo.x);
    hvi_pixel(R.y, G.y, B.y, k, Ro.y, Go.y, Bo.y);
    hvi_pixel(R.z, G.z, B.z, k, Ro.z, Go.z, Bo.z);
    hvi_pixel(R.w, G.w, B.w, k, Ro.w, Go.w, Bo.w);

    *reinterpret_cast<float4*>(out + base)           = Ro;
    *reinterpret_cast<float4*>(out + base + 1048576) = Go;
    *reinterpret_cast<float4*>(out + base + 2097152) = Bo;
}

extern "C" void kernel_launch(void* const* d_in, const int* in_sizes, int n_in,
                              void* d_out, int out_size, void* d_ws, size_t ws_size,
                              hipStream_t stream)
{
    const float* img  = (const float*)d_in[0];
    const float* kptr = (const float*)d_in[1];
    float* out = (float*)d_out;

    int total   = in_sizes[0];        // 16*3*1024*1024 = 50331648
    int ngroups = total / 12;         // pixels/4 = 4194304
    int block   = 256;
    int grid    = (ngroups + block - 1) / block;

    rgb_hvi_kernel<<<grid, block, 0, stream>>>(img, kptr, out, ngroups);
}